// Round 2
// baseline (11787.405 us; speedup 1.0000x reference)
//
#include <hip/hip_runtime.h>
#include <cstdint>
#include <cstddef>

typedef __attribute__((ext_vector_type(8))) short bf16x8;
typedef __attribute__((ext_vector_type(8))) unsigned short ushort8;
typedef __attribute__((ext_vector_type(4))) float f32x4;

// round-to-nearest-even fp32 -> bf16 bits
__device__ __forceinline__ unsigned short f2bf(float f){
  unsigned int u = __float_as_uint(f);
  unsigned int lsb = (u >> 16) & 1u;
  u += 0x7fffu + lsb;
  return (unsigned short)(u >> 16);
}

// ---------------- weight packing ----------------
// conv weights (COUT,CIN,3) -> [o][kk][ci] fp32
__global__ __launch_bounds__(256) void pack_w_kernel(const float* __restrict__ W,
                                                     float* __restrict__ Wp, int COUT, int CIN){
  int idx = blockIdx.x*256 + threadIdx.x;
  int tot = COUT*CIN*3;
  if (idx >= tot) return;
  int o = idx/(CIN*3); int r = idx - o*(CIN*3); int kk = r/CIN; int ci = r - kk*CIN;
  Wp[idx] = W[(o*CIN + ci)*3 + kk];
}

// h0 weights: Bw[p][k] bf16 ; k<64 -> Wp[p,k,0] ; k>=64 -> Wp[p,k-64,1]
__global__ __launch_bounds__(256) void pack_wp_kernel(const float* __restrict__ Wp,
                                                      unsigned short* __restrict__ Bw){
  int idx = blockIdx.x*256 + threadIdx.x;
  if (idx >= 64*128) return;
  int p = idx >> 7, k = idx & 127;
  float v = (k < 64) ? Wp[p*128 + k*2] : Wp[p*128 + (k-64)*2 + 1];
  Bw[idx] = f2bf(v);
}

__global__ __launch_bounds__(256) void f2bf_kernel(const float* __restrict__ src,
                                                   unsigned short* __restrict__ dst, int n){
  int i = blockIdx.x*256 + threadIdx.x;
  if (i < n) dst[i] = f2bf(src[i]);
}

// ---------------- branch MLP: x0 -> 64 -> 128 -> 256, writes f into Hcat[16384:] ----------------
__global__ __launch_bounds__(256) void branch_kernel(const float* __restrict__ x,
    const float* __restrict__ Wb1, const float* __restrict__ bb1,
    const float* __restrict__ Wb2, const float* __restrict__ bb2,
    const float* __restrict__ Wb3, const float* __restrict__ bb3,
    unsigned short* __restrict__ Hcat){
  __shared__ float s0[64], s1[64], s2[128];
  const int b = blockIdx.x, tid = threadIdx.x;
  const float* xb = x + (size_t)b*16384;
  if (tid < 64) s0[tid] = xb[tid];
  __syncthreads();
  if (tid < 64){
    float a = bb1[tid];
    for (int k=0;k<64;k++) a = fmaf(Wb1[tid*64+k], s0[k], a);
    s1[tid] = fmaxf(a, 0.f);
  }
  __syncthreads();
  if (tid < 128){
    float a = bb2[tid];
    for (int k=0;k<64;k++) a = fmaf(Wb2[tid*64+k], s1[k], a);
    s2[tid] = fmaxf(a, 0.f);
  }
  __syncthreads();
  float a = bb3[tid];
  for (int k=0;k<128;k++) a = fmaf(Wb3[tid*128+k], s2[k], a);
  Hcat[(size_t)b*16640 + 16384 + tid] = f2bf(fmaxf(a, 0.f));
}

// ---------------- h0 as MFMA GEMM: M=Bc*255 rows (b,c'), N=64 (p), K=128 ([x0|x_{c'+1}]) ----------------
__global__ __launch_bounds__(256) void h0_gemm_kernel(const float* __restrict__ x,
    const unsigned short* __restrict__ Bw, const float* __restrict__ bp,
    float* __restrict__ h0){
  __shared__ __align__(16) char sAraw[128*256];   // 128 rows x 128 bf16 (256B rows), xor-swizzled
  __shared__ __align__(16) char sBraw[64*256];
  const int tid = threadIdx.x;
  const int m0 = blockIdx.x*128;
  // stage A (fp32 -> bf16), 4096 ushort4-slots (each thread: 4 floats -> 4 bf16 = 8B)
  #pragma unroll
  for (int i=0;i<16;i++){
    int j = tid + 256*i;
    int row = j >> 5, q = j & 31;
    int m = m0 + row;
    int b = m / 255, c = m - b*255;
    const float* xb = x + (size_t)b*16384;
    int k = q*4;
    const float* src = (k < 64) ? (xb + k) : (xb + (c+1)*64 + (k-64));
    float4 v = *(const float4*)src;
    ushort4 u; u.x=f2bf(v.x); u.y=f2bf(v.y); u.z=f2bf(v.z); u.w=f2bf(v.w);
    *(ushort4*)(sAraw + row*256 + ((k*2) ^ ((row&7)<<4))) = u;
  }
  // stage B (already bf16): 1024 slots of 8 bf16 = 16B each
  #pragma unroll
  for (int i=0;i<4;i++){
    int j = tid + 256*i;
    int row = j >> 4, q = j & 15;
    int k = q*8;                      // element offset, 8 bf16 = 16B
    ushort8 u = *(const ushort8*)(Bw + row*128 + k);
    *(ushort8*)(sBraw + row*256 + ((k*2) ^ ((row&7)<<4))) = u;
  }
  __syncthreads();
  const int lane = tid & 63, wid = tid >> 6;
  const int lr = lane & 15, lg = lane >> 4;
  f32x4 zero = {0.f,0.f,0.f,0.f};
  f32x4 acc[2][4];
  #pragma unroll
  for (int a=0;a<2;a++){ acc[a][0]=zero; acc[a][1]=zero; acc[a][2]=zero; acc[a][3]=zero; }
  #pragma unroll
  for (int ks=0; ks<4; ks++){
    int k = ks*32 + lg*8;
    bf16x8 af[2], bfr[4];
    #pragma unroll
    for (int f=0; f<2; f++){
      int row = wid*32 + f*16 + lr;
      af[f] = *(const bf16x8*)(sAraw + row*256 + ((k*2) ^ ((row&7)<<4)));
    }
    #pragma unroll
    for (int f=0; f<4; f++){
      int row = f*16 + lr;
      bfr[f] = *(const bf16x8*)(sBraw + row*256 + ((k*2) ^ ((row&7)<<4)));
    }
    #pragma unroll
    for (int fi=0; fi<2; fi++)
      #pragma unroll
      for (int fj=0; fj<4; fj++)
        acc[fi][fj] = __builtin_amdgcn_mfma_f32_16x16x32_bf16(af[fi], bfr[fj], acc[fi][fj], 0,0,0);
  }
  #pragma unroll
  for (int fi=0; fi<2; fi++)
    #pragma unroll
    for (int fj=0; fj<4; fj++)
      #pragma unroll
      for (int j=0;j<4;j++){
        int m = m0 + wid*32 + fi*16 + lg*4 + j;
        int n = fj*16 + lr;
        h0[(size_t)m*64 + n] = fmaxf(acc[fi][fj][j] + bp[n], 0.f);
      }
}

// ---------------- generic fp32 conv1d (k=3,pad=1) + relu ----------------
template<int CIN,int COUT,int STRIDE,int LIN,int LOUT,int TT,bool CM_BF16>
__global__ __launch_bounds__(256) void conv_relu_kernel(
    const float* __restrict__ in, const float* __restrict__ Wp,
    const float* __restrict__ bias, float* __restrict__ outf,
    unsigned short* __restrict__ outbf){
  constexpr int NROWS = (TT-1)*STRIDE + 3;
  constexpr int TPG = COUT/8;        // threads per output-position group (8 outch each)
  constexpr int NT = 256/TPG;        // positions handled concurrently
  constexpr int NS = TT/NT;          // per-thread position blocking
  __shared__ __align__(16) float sIn[NROWS*CIN];
  const int b = blockIdx.y;
  const int t0 = blockIdx.x*TT;
  const int tid = threadIdx.x;
  const float* inb = in + (size_t)b*LIN*CIN;
  const int base = t0*STRIDE - 1;
  for (int j = tid; j < NROWS*CIN/4; j += 256){
    int row = j/(CIN/4), q = j - row*(CIN/4);
    int pos = base + row;
    float4 v = make_float4(0.f,0.f,0.f,0.f);
    if (pos >= 0 && pos < LIN) v = ((const float4*)(inb + (size_t)pos*CIN))[q];
    ((float4*)sIn)[j] = v;
  }
  __syncthreads();
  const int og = (tid % TPG)*8;
  const int tb = tid / TPG;
  float acc[NS][8];
  #pragma unroll
  for (int s=0;s<NS;s++)
    #pragma unroll
    for (int j=0;j<8;j++) acc[s][j] = bias[og+j];
  const float* wb = Wp + (size_t)og*3*CIN;
  #pragma unroll
  for (int kk=0; kk<3; kk++){
    for (int c4=0; c4<CIN/4; c4++){
      float4 w[8];
      #pragma unroll
      for (int j=0;j<8;j++) w[j] = ((const float4*)(wb + (j*3+kk)*CIN))[c4];
      #pragma unroll
      for (int s=0;s<NS;s++){
        const float4 xv = ((const float4*)(sIn + ((tb + s*NT)*STRIDE + kk)*CIN))[c4];
        #pragma unroll
        for (int j=0;j<8;j++){
          acc[s][j] = fmaf(xv.x, w[j].x, acc[s][j]);
          acc[s][j] = fmaf(xv.y, w[j].y, acc[s][j]);
          acc[s][j] = fmaf(xv.z, w[j].z, acc[s][j]);
          acc[s][j] = fmaf(xv.w, w[j].w, acc[s][j]);
        }
      }
    }
  }
  #pragma unroll
  for (int s=0;s<NS;s++){
    int t = t0 + tb + s*NT;
    if (t < LOUT){
      if (!CM_BF16){
        float4 o0, o1;
        o0.x=fmaxf(acc[s][0],0.f); o0.y=fmaxf(acc[s][1],0.f); o0.z=fmaxf(acc[s][2],0.f); o0.w=fmaxf(acc[s][3],0.f);
        o1.x=fmaxf(acc[s][4],0.f); o1.y=fmaxf(acc[s][5],0.f); o1.z=fmaxf(acc[s][6],0.f); o1.w=fmaxf(acc[s][7],0.f);
        float* op = outf + ((size_t)b*LOUT + t)*COUT + og;
        ((float4*)op)[0] = o0; ((float4*)op)[1] = o1;
      } else {
        // channel-major into Hcat: [b][o*64 + t] (LOUT==64 here)
        unsigned short* hp = outbf + (size_t)b*16640 + t;
        #pragma unroll
        for (int j=0;j<8;j++) hp[(size_t)(og+j)*64] = f2bf(fmaxf(acc[s][j],0.f));
      }
    }
  }
}

// ---------------- fc1: bf16 MFMA GEMM, M=Bc, N=1024, K=16640, K-split 2 ----------------
__global__ __launch_bounds__(256) void fc1_gemm_kernel(
    const unsigned short* __restrict__ A, const unsigned short* __restrict__ Bw,
    float* __restrict__ zp, int zoff){
  __shared__ __align__(16) char sAraw[128*128];   // 128 rows x 64 bf16 (128B rows), xor-swizzled
  __shared__ __align__(16) char sBraw[128*128];
  const int tid = threadIdx.x;
  const int n0 = blockIdx.x*128;
  const int m0 = blockIdx.y*128;
  const int kz = blockIdx.z;
  const int lane = tid & 63, wid = tid >> 6;
  const int wm = wid >> 1, wn = wid & 1;
  const int lr = lane & 15, lg = lane >> 4;
  const int srow = tid >> 3;     // 0..31
  const int sk = (tid & 7)*8;    // bf16 k offset within 64 (8 bf16 = 16B per thread)
  f32x4 zero = {0.f,0.f,0.f,0.f};
  f32x4 acc[4][4];
  #pragma unroll
  for (int i=0;i<4;i++){ acc[i][0]=zero; acc[i][1]=zero; acc[i][2]=zero; acc[i][3]=zero; }
  const int kc0 = kz*130, kc1 = kc0 + 130;
  for (int kc=kc0; kc<kc1; kc++){
    const size_t k0 = (size_t)kc*64;
    __syncthreads();
    #pragma unroll
    for (int r=0;r<4;r++){
      int row = srow + r*32;
      ushort8 ua = *(const ushort8*)(A  + (size_t)(m0+row)*16640 + k0 + sk);
      *(ushort8*)(sAraw + row*128 + ((sk*2) ^ ((row&7)<<4))) = ua;
      ushort8 ub = *(const ushort8*)(Bw + (size_t)(n0+row)*16640 + k0 + sk);
      *(ushort8*)(sBraw + row*128 + ((sk*2) ^ ((row&7)<<4))) = ub;
    }
    __syncthreads();
    #pragma unroll
    for (int ks=0; ks<2; ks++){
      const int k = ks*32 + lg*8;
      bf16x8 af[4], bfr[4];
      #pragma unroll
      for (int f=0;f<4;f++){
        int rowa = wm*64 + f*16 + lr;
        af[f]  = *(const bf16x8*)(sAraw + rowa*128 + ((k*2) ^ ((rowa&7)<<4)));
        int rowb = wn*64 + f*16 + lr;
        bfr[f] = *(const bf16x8*)(sBraw + rowb*128 + ((k*2) ^ ((rowb&7)<<4)));
      }
      #pragma unroll
      for (int fi=0;fi<4;fi++)
        #pragma unroll
        for (int fj=0;fj<4;fj++)
          acc[fi][fj] = __builtin_amdgcn_mfma_f32_16x16x32_bf16(af[fi], bfr[fj], acc[fi][fj], 0,0,0);
    }
  }
  float* zo = zp + (size_t)kz*zoff;
  #pragma unroll
  for (int fi=0;fi<4;fi++)
    #pragma unroll
    for (int fj=0;fj<4;fj++)
      #pragma unroll
      for (int j=0;j<4;j++){
        int m = m0 + wm*64 + fi*16 + lg*4 + j;
        int n = n0 + wn*64 + fj*16 + lr;
        zo[(size_t)m*1024 + n] = acc[fi][fj][j];
      }
}

// ---------------- fc2: combine K-split partials, bias+relu, then 1024->2 ----------------
__global__ __launch_bounds__(64) void fc2_kernel(const float* __restrict__ zp, int zoff,
    const float* __restrict__ bfc1, const float* __restrict__ Wfc2,
    const float* __restrict__ bfc2, float* __restrict__ out){
  const int b = blockIdx.x, l = threadIdx.x;
  const float* z0 = zp + (size_t)b*1024;
  const float* z1 = z0 + zoff;
  float a0 = 0.f, a1 = 0.f;
  for (int k=l; k<1024; k+=64){
    float zv = fmaxf(z0[k] + z1[k] + bfc1[k], 0.f);
    a0 = fmaf(zv, Wfc2[k], a0);
    a1 = fmaf(zv, Wfc2[1024+k], a1);
  }
  #pragma unroll
  for (int m=32; m>=1; m>>=1){ a0 += __shfl_xor(a0, m, 64); a1 += __shfl_xor(a1, m, 64); }
  if (l == 0){ out[(size_t)b*2] = a0 + bfc2[0]; out[(size_t)b*2+1] = a1 + bfc2[1]; }
}

extern "C" void kernel_launch(void* const* d_in, const int* in_sizes, int n_in,
                              void* d_out, int out_size, void* d_ws, size_t ws_size,
                              hipStream_t stream){
  const float* x    = (const float*)d_in[0];
  const float* Wp   = (const float*)d_in[1];
  const float* bp   = (const float*)d_in[2];
  const float* W1   = (const float*)d_in[3];
  const float* b1   = (const float*)d_in[4];
  const float* W2   = (const float*)d_in[5];
  const float* b2   = (const float*)d_in[6];
  const float* W3   = (const float*)d_in[7];
  const float* b3   = (const float*)d_in[8];
  const float* Wb1  = (const float*)d_in[9];
  const float* bb1  = (const float*)d_in[10];
  const float* Wb2  = (const float*)d_in[11];
  const float* bb2  = (const float*)d_in[12];
  const float* Wb3  = (const float*)d_in[13];
  const float* bb3  = (const float*)d_in[14];
  const float* Wfc1 = (const float*)d_in[15];
  const float* bfc1 = (const float*)d_in[16];
  const float* Wfc2 = (const float*)d_in[17];
  const float* bfc2 = (const float*)d_in[18];
  float* out = (float*)d_out;

  size_t off = 0;
  char* basep = (char*)d_ws;
  auto carve = [&](size_t bytes)->char*{
    char* q = basep + off; off += (bytes + 255) & ~(size_t)255; return q;
  };
  float* W1p = (float*)carve((size_t)128*64*3*4);
  float* W2p = (float*)carve((size_t)256*128*3*4);
  float* W3p = (float*)carve((size_t)256*256*3*4);
  unsigned short* Bwp   = (unsigned short*)carve((size_t)64*128*2);
  unsigned short* Wfc1b = (unsigned short*)carve((size_t)1024*16640*2);
  size_t fixed = off;

  // choose smallest chunking that fits ws (per-chunk bytes = Bc*303104 + slop)
  int NC = 16;
  for (int nc : {1,2,4,8,16}){
    size_t Bc_ = 2048/nc;
    size_t need = fixed + Bc_*((size_t)131072+130560+33280+8192) + 8*256;
    if (need <= ws_size){ NC = nc; break; }
  }
  const int Bc = 2048/NC;
  float*          reg0  = (float*)carve((size_t)Bc*131072);          // h0 (Bc*65280B) then h2 (Bc*131072B)
  float*          h1buf = (float*)carve((size_t)Bc*130560);
  unsigned short* Hcat  = (unsigned short*)carve((size_t)Bc*33280);  // [Bc][16640] bf16
  float*          zp    = (float*)carve((size_t)Bc*8192);            // 2 x [Bc][1024]
  const int zoff = Bc*1024;

  hipLaunchKernelGGL(pack_w_kernel, dim3((128*64*3+255)/256), dim3(256), 0, stream, W1, W1p, 128, 64);
  hipLaunchKernelGGL(pack_w_kernel, dim3((256*128*3+255)/256), dim3(256), 0, stream, W2, W2p, 256, 128);
  hipLaunchKernelGGL(pack_w_kernel, dim3((256*256*3+255)/256), dim3(256), 0, stream, W3, W3p, 256, 256);
  hipLaunchKernelGGL(pack_wp_kernel, dim3(32), dim3(256), 0, stream, Wp, Bwp);
  hipLaunchKernelGGL(f2bf_kernel, dim3((17039360+255)/256), dim3(256), 0, stream, Wfc1, Wfc1b, 17039360);

  for (int c = 0; c < NC; ++c){
    const float* xc = x + (size_t)c*Bc*16384;
    hipLaunchKernelGGL(branch_kernel, dim3(Bc), dim3(256), 0, stream,
                       xc, Wb1, bb1, Wb2, bb2, Wb3, bb3, Hcat);
    hipLaunchKernelGGL(h0_gemm_kernel, dim3(Bc*255/128), dim3(256), 0, stream, xc, Bwp, bp, reg0);
    hipLaunchKernelGGL((conv_relu_kernel<64,128,1,255,255,32,false>), dim3(8,Bc), dim3(256), 0, stream,
                       reg0, W1p, b1, h1buf, (unsigned short*)nullptr);
    hipLaunchKernelGGL((conv_relu_kernel<128,256,2,255,128,32,false>), dim3(4,Bc), dim3(256), 0, stream,
                       h1buf, W2p, b2, reg0, (unsigned short*)nullptr);
    hipLaunchKernelGGL((conv_relu_kernel<256,256,2,128,64,16,true>), dim3(4,Bc), dim3(256), 0, stream,
                       reg0, W3p, b3, (float*)nullptr, Hcat);
    hipLaunchKernelGGL(fc1_gemm_kernel, dim3(8, Bc/128, 2), dim3(256), 0, stream, Hcat, Wfc1b, zp, zoff);
    hipLaunchKernelGGL(fc2_kernel, dim3(Bc), dim3(64), 0, stream, zp, zoff, bfc1, Wfc2, bfc2, out + (size_t)c*Bc*2);
  }
}

// Round 3
// 751.701 us; speedup vs baseline: 15.6810x; 15.6810x over previous
//
#include <hip/hip_runtime.h>
#include <cstdint>
#include <cstddef>

typedef __attribute__((ext_vector_type(8))) short bf16x8;
typedef __attribute__((ext_vector_type(8))) unsigned short ushort8;
typedef __attribute__((ext_vector_type(4))) float f32x4;

// round-to-nearest-even fp32 -> bf16 bits
__device__ __forceinline__ unsigned short f2bf(float f){
  unsigned int u = __float_as_uint(f);
  unsigned int lsb = (u >> 16) & 1u;
  u += 0x7fffu + lsb;
  return (unsigned short)(u >> 16);
}

// ---------------- weight packing ----------------
// conv weights (COUT,CIN,3) fp32 -> [o][kk][ci] bf16
__global__ __launch_bounds__(256) void pack_w_bf16_kernel(const float* __restrict__ W,
                                                          unsigned short* __restrict__ Wb,
                                                          int COUT, int CIN){
  int idx = blockIdx.x*256 + threadIdx.x;
  int tot = COUT*CIN*3;
  if (idx >= tot) return;
  int o = idx/(CIN*3); int r = idx - o*(CIN*3); int kk = r/CIN; int ci = r - kk*CIN;
  Wb[idx] = f2bf(W[(o*CIN + ci)*3 + kk]);
}

// h0 weights: Bw[p][k] bf16 ; k<64 -> Wp[p,k,0] ; k>=64 -> Wp[p,k-64,1]
__global__ __launch_bounds__(256) void pack_wp_kernel(const float* __restrict__ Wp,
                                                      unsigned short* __restrict__ Bw){
  int idx = blockIdx.x*256 + threadIdx.x;
  if (idx >= 64*128) return;
  int p = idx >> 7, k = idx & 127;
  float v = (k < 64) ? Wp[p*128 + k*2] : Wp[p*128 + (k-64)*2 + 1];
  Bw[idx] = f2bf(v);
}

__global__ __launch_bounds__(256) void f2bf_kernel(const float* __restrict__ src,
                                                   unsigned short* __restrict__ dst, int n){
  int i = blockIdx.x*256 + threadIdx.x;
  if (i < n) dst[i] = f2bf(src[i]);
}

// ---------------- branch MLP: x0 -> 64 -> 128 -> 256, writes f into Hcat[16384:] ----------------
__global__ __launch_bounds__(256) void branch_kernel(const float* __restrict__ x,
    const float* __restrict__ Wb1, const float* __restrict__ bb1,
    const float* __restrict__ Wb2, const float* __restrict__ bb2,
    const float* __restrict__ Wb3, const float* __restrict__ bb3,
    unsigned short* __restrict__ Hcat){
  __shared__ float s0[64], s1[64], s2[128];
  const int b = blockIdx.x, tid = threadIdx.x;
  const float* xb = x + (size_t)b*16384;
  if (tid < 64) s0[tid] = xb[tid];
  __syncthreads();
  if (tid < 64){
    float a = bb1[tid];
    for (int k=0;k<64;k++) a = fmaf(Wb1[tid*64+k], s0[k], a);
    s1[tid] = fmaxf(a, 0.f);
  }
  __syncthreads();
  if (tid < 128){
    float a = bb2[tid];
    for (int k=0;k<64;k++) a = fmaf(Wb2[tid*64+k], s1[k], a);
    s2[tid] = fmaxf(a, 0.f);
  }
  __syncthreads();
  float a = bb3[tid];
  for (int k=0;k<128;k++) a = fmaf(Wb3[tid*128+k], s2[k], a);
  Hcat[(size_t)b*16640 + 16384 + tid] = f2bf(fmaxf(a, 0.f));
}

// ---------------- h0 as MFMA GEMM: M=Bc*255 rows (b,pos), N=64 (p), K=128 ([x0|x_{pos+1}]) ----------------
// output: bf16 row-major [b][pos][64]
__global__ __launch_bounds__(256) void h0_gemm_kernel(const float* __restrict__ x,
    const unsigned short* __restrict__ Bw, const float* __restrict__ bp,
    unsigned short* __restrict__ h0o){
  __shared__ __align__(16) char sAraw[128*256];   // 128 rows x 128 bf16 (256B rows), xor-swizzled
  __shared__ __align__(16) char sBraw[64*256];
  const int tid = threadIdx.x;
  const int m0 = blockIdx.x*128;
  #pragma unroll
  for (int i=0;i<16;i++){
    int j = tid + 256*i;
    int row = j >> 5, q = j & 31;
    int m = m0 + row;
    int b = m / 255, c = m - b*255;
    const float* xb = x + (size_t)b*16384;
    int k = q*4;
    const float* src = (k < 64) ? (xb + k) : (xb + (c+1)*64 + (k-64));
    float4 v = *(const float4*)src;
    ushort4 u; u.x=f2bf(v.x); u.y=f2bf(v.y); u.z=f2bf(v.z); u.w=f2bf(v.w);
    *(ushort4*)(sAraw + row*256 + ((k*2) ^ ((row&7)<<4))) = u;
  }
  #pragma unroll
  for (int i=0;i<4;i++){
    int j = tid + 256*i;
    int row = j >> 4, q = j & 15;
    int k = q*8;
    ushort8 u = *(const ushort8*)(Bw + row*128 + k);
    *(ushort8*)(sBraw + row*256 + ((k*2) ^ ((row&7)<<4))) = u;
  }
  __syncthreads();
  const int lane = tid & 63, wid = tid >> 6;
  const int lr = lane & 15, lg = lane >> 4;
  f32x4 zero = {0.f,0.f,0.f,0.f};
  f32x4 acc[2][4];
  #pragma unroll
  for (int a=0;a<2;a++){ acc[a][0]=zero; acc[a][1]=zero; acc[a][2]=zero; acc[a][3]=zero; }
  #pragma unroll
  for (int ks=0; ks<4; ks++){
    int k = ks*32 + lg*8;
    bf16x8 af[2], bfr[4];
    #pragma unroll
    for (int f=0; f<2; f++){
      int row = wid*32 + f*16 + lr;
      af[f] = *(const bf16x8*)(sAraw + row*256 + ((k*2) ^ ((row&7)<<4)));
    }
    #pragma unroll
    for (int f=0; f<4; f++){
      int row = f*16 + lr;
      bfr[f] = *(const bf16x8*)(sBraw + row*256 + ((k*2) ^ ((row&7)<<4)));
    }
    #pragma unroll
    for (int fi=0; fi<2; fi++)
      #pragma unroll
      for (int fj=0; fj<4; fj++)
        acc[fi][fj] = __builtin_amdgcn_mfma_f32_16x16x32_bf16(af[fi], bfr[fj], acc[fi][fj], 0,0,0);
  }
  #pragma unroll
  for (int fi=0; fi<2; fi++)
    #pragma unroll
    for (int fj=0; fj<4; fj++)
      #pragma unroll
      for (int j=0;j<4;j++){
        int m = m0 + wid*32 + fi*16 + lg*4 + j;
        int n = fj*16 + lr;
        h0o[(size_t)m*64 + n] = f2bf(fmaxf(acc[fi][fj][j] + bp[n], 0.f));
      }
}

// ---------------- implicit-GEMM bf16 conv1d (k=3,pad=1) + relu ----------------
// in: bf16 [b][LIN][CIN] ; Wb: bf16 [COUT][3][CIN] ; out: bf16 [b][LOUT][COUT]
// (or TO_HCAT: [b][16640] channel-major n*64+m)
template<int CIN,int COUT,int S,int LIN,int LOUT,int BM,int BN,int WN,bool TO_HCAT>
__global__ __launch_bounds__(256) void conv_gemm_kernel(
    const unsigned short* __restrict__ in, const unsigned short* __restrict__ Wb,
    const float* __restrict__ bias, unsigned short* __restrict__ out){
  constexpr int MT = (LOUT + BM - 1)/BM;     // M tiles per batch
  __shared__ __align__(16) char sA[BM*128];  // BM rows x 64 bf16, swizzled
  __shared__ __align__(16) char sB[BN*128];
  const int tid = threadIdx.x;
  const int b  = blockIdx.y;
  const int mt = blockIdx.x % MT;
  const int nt = blockIdx.x / MT;
  const int m0 = mt*BM, n0 = nt*BN;
  const unsigned short* inb = in + (size_t)b*LIN*CIN;
  const int lane = tid & 63, wid = tid >> 6;
  const int wm = wid / WN, wn = wid % WN;
  const int lr = lane & 15, lg = lane >> 4;
  f32x4 zero = {0.f,0.f,0.f,0.f};
  f32x4 acc[4][4];
  #pragma unroll
  for (int i=0;i<4;i++){ acc[i][0]=zero; acc[i][1]=zero; acc[i][2]=zero; acc[i][3]=zero; }
  #pragma unroll
  for (int kk=0; kk<3; kk++){
    #pragma unroll
    for (int cc=0; cc<CIN/64; cc++){
      __syncthreads();
      // stage A: implicit im2col, row = output position, 64 bf16 of k
      #pragma unroll
      for (int p=0; p<BM/32; p++){
        int slot = tid + p*256;
        int row = slot >> 3, c8 = slot & 7;
        int pos = (m0 + row)*S - 1 + kk;
        ushort8 v = {0,0,0,0,0,0,0,0};
        if (pos >= 0 && pos < LIN)
          v = *(const ushort8*)(inb + (size_t)pos*CIN + cc*64 + c8*8);
        *(ushort8*)(sA + row*128 + ((c8*16) ^ ((row&7)<<4))) = v;
      }
      // stage B: weights rows = out channel
      #pragma unroll
      for (int p=0; p<BN/32; p++){
        int slot = tid + p*256;
        int row = slot >> 3, c8 = slot & 7;
        ushort8 v = *(const ushort8*)(Wb + ((size_t)(n0+row)*3 + kk)*CIN + cc*64 + c8*8);
        *(ushort8*)(sB + row*128 + ((c8*16) ^ ((row&7)<<4))) = v;
      }
      __syncthreads();
      #pragma unroll
      for (int ks=0; ks<2; ks++){
        const int k = ks*32 + lg*8;
        bf16x8 af[4], bf[4];
        #pragma unroll
        for (int f=0;f<4;f++){
          int ra = wm*64 + f*16 + lr;
          af[f] = *(const bf16x8*)(sA + ra*128 + ((k*2) ^ ((ra&7)<<4)));
          int rb = wn*64 + f*16 + lr;
          bf[f] = *(const bf16x8*)(sB + rb*128 + ((k*2) ^ ((rb&7)<<4)));
        }
        #pragma unroll
        for (int fi=0;fi<4;fi++)
          #pragma unroll
          for (int fj=0;fj<4;fj++)
            acc[fi][fj] = __builtin_amdgcn_mfma_f32_16x16x32_bf16(af[fi], bf[fj], acc[fi][fj], 0,0,0);
      }
    }
  }
  unsigned short* outb = TO_HCAT ? (out + (size_t)b*16640) : (out + (size_t)b*LOUT*COUT);
  #pragma unroll
  for (int fi=0;fi<4;fi++)
    #pragma unroll
    for (int fj=0;fj<4;fj++)
      #pragma unroll
      for (int j=0;j<4;j++){
        int m = m0 + wm*64 + fi*16 + lg*4 + j;
        int n = n0 + wn*64 + fj*16 + lr;
        if (m < LOUT){
          float val = fmaxf(acc[fi][fj][j] + bias[n], 0.f);
          if (TO_HCAT) outb[(size_t)n*64 + m] = f2bf(val);
          else         outb[(size_t)m*COUT + n] = f2bf(val);
        }
      }
}

// ---------------- fc1: bf16 MFMA GEMM, M=Bc, N=1024, K=16640, K-split 2 ----------------
__global__ __launch_bounds__(256) void fc1_gemm_kernel(
    const unsigned short* __restrict__ A, const unsigned short* __restrict__ Bw,
    float* __restrict__ zp, int zoff){
  __shared__ __align__(16) char sAraw[128*128];
  __shared__ __align__(16) char sBraw[128*128];
  const int tid = threadIdx.x;
  const int n0 = blockIdx.x*128;
  const int m0 = blockIdx.y*128;
  const int kz = blockIdx.z;
  const int lane = tid & 63, wid = tid >> 6;
  const int wm = wid >> 1, wn = wid & 1;
  const int lr = lane & 15, lg = lane >> 4;
  const int srow = tid >> 3;
  const int sk = (tid & 7)*8;
  f32x4 zero = {0.f,0.f,0.f,0.f};
  f32x4 acc[4][4];
  #pragma unroll
  for (int i=0;i<4;i++){ acc[i][0]=zero; acc[i][1]=zero; acc[i][2]=zero; acc[i][3]=zero; }
  const int kc0 = kz*130, kc1 = kc0 + 130;
  for (int kc=kc0; kc<kc1; kc++){
    const size_t k0 = (size_t)kc*64;
    __syncthreads();
    #pragma unroll
    for (int r=0;r<4;r++){
      int row = srow + r*32;
      ushort8 ua = *(const ushort8*)(A  + (size_t)(m0+row)*16640 + k0 + sk);
      *(ushort8*)(sAraw + row*128 + ((sk*2) ^ ((row&7)<<4))) = ua;
      ushort8 ub = *(const ushort8*)(Bw + (size_t)(n0+row)*16640 + k0 + sk);
      *(ushort8*)(sBraw + row*128 + ((sk*2) ^ ((row&7)<<4))) = ub;
    }
    __syncthreads();
    #pragma unroll
    for (int ks=0; ks<2; ks++){
      const int k = ks*32 + lg*8;
      bf16x8 af[4], bfr[4];
      #pragma unroll
      for (int f=0;f<4;f++){
        int rowa = wm*64 + f*16 + lr;
        af[f]  = *(const bf16x8*)(sAraw + rowa*128 + ((k*2) ^ ((rowa&7)<<4)));
        int rowb = wn*64 + f*16 + lr;
        bfr[f] = *(const bf16x8*)(sBraw + rowb*128 + ((k*2) ^ ((rowb&7)<<4)));
      }
      #pragma unroll
      for (int fi=0;fi<4;fi++)
        #pragma unroll
        for (int fj=0;fj<4;fj++)
          acc[fi][fj] = __builtin_amdgcn_mfma_f32_16x16x32_bf16(af[fi], bfr[fj], acc[fi][fj], 0,0,0);
    }
  }
  float* zo = zp + (size_t)kz*zoff;
  #pragma unroll
  for (int fi=0;fi<4;fi++)
    #pragma unroll
    for (int fj=0;fj<4;fj++)
      #pragma unroll
      for (int j=0;j<4;j++){
        int m = m0 + wm*64 + fi*16 + lg*4 + j;
        int n = n0 + wn*64 + fj*16 + lr;
        zo[(size_t)m*1024 + n] = acc[fi][fj][j];
      }
}

// ---------------- fc2: combine K-split partials, bias+relu, then 1024->2 ----------------
__global__ __launch_bounds__(64) void fc2_kernel(const float* __restrict__ zp, int zoff,
    const float* __restrict__ bfc1, const float* __restrict__ Wfc2,
    const float* __restrict__ bfc2, float* __restrict__ out){
  const int b = blockIdx.x, l = threadIdx.x;
  const float* z0 = zp + (size_t)b*1024;
  const float* z1 = z0 + zoff;
  float a0 = 0.f, a1 = 0.f;
  for (int k=l; k<1024; k+=64){
    float zv = fmaxf(z0[k] + z1[k] + bfc1[k], 0.f);
    a0 = fmaf(zv, Wfc2[k], a0);
    a1 = fmaf(zv, Wfc2[1024+k], a1);
  }
  #pragma unroll
  for (int m=32; m>=1; m>>=1){ a0 += __shfl_xor(a0, m, 64); a1 += __shfl_xor(a1, m, 64); }
  if (l == 0){ out[(size_t)b*2] = a0 + bfc2[0]; out[(size_t)b*2+1] = a1 + bfc2[1]; }
}

extern "C" void kernel_launch(void* const* d_in, const int* in_sizes, int n_in,
                              void* d_out, int out_size, void* d_ws, size_t ws_size,
                              hipStream_t stream){
  const float* x    = (const float*)d_in[0];
  const float* Wp   = (const float*)d_in[1];
  const float* bp   = (const float*)d_in[2];
  const float* W1   = (const float*)d_in[3];
  const float* b1   = (const float*)d_in[4];
  const float* W2   = (const float*)d_in[5];
  const float* b2   = (const float*)d_in[6];
  const float* W3   = (const float*)d_in[7];
  const float* b3   = (const float*)d_in[8];
  const float* Wb1  = (const float*)d_in[9];
  const float* bb1  = (const float*)d_in[10];
  const float* Wb2  = (const float*)d_in[11];
  const float* bb2  = (const float*)d_in[12];
  const float* Wb3  = (const float*)d_in[13];
  const float* bb3  = (const float*)d_in[14];
  const float* Wfc1 = (const float*)d_in[15];
  const float* bfc1 = (const float*)d_in[16];
  const float* Wfc2 = (const float*)d_in[17];
  const float* bfc2 = (const float*)d_in[18];
  float* out = (float*)d_out;

  size_t off = 0;
  char* basep = (char*)d_ws;
  auto carve = [&](size_t bytes)->char*{
    char* q = basep + off; off += (bytes + 255) & ~(size_t)255; return q;
  };
  unsigned short* W1b   = (unsigned short*)carve((size_t)128*3*64*2);
  unsigned short* W2b   = (unsigned short*)carve((size_t)256*3*128*2);
  unsigned short* W3b   = (unsigned short*)carve((size_t)256*3*256*2);
  unsigned short* Bwp   = (unsigned short*)carve((size_t)64*128*2);
  unsigned short* Wfc1b = (unsigned short*)carve((size_t)1024*16640*2);
  size_t fixed = off;

  // per-chunk bytes: buf1(h0/c2)=Bc*65536, buf2(c1)=Bc*65280, Hcat=Bc*33280, zp=Bc*8192
  int NC = 16;
  for (int nc : {1,2,4,8,16}){
    size_t Bc_ = 2048/nc;
    size_t need = fixed + Bc_*((size_t)65536+65280+33280+8192) + 8*256;
    if (need <= ws_size){ NC = nc; break; }
  }
  const int Bc = 2048/NC;
  unsigned short* buf1 = (unsigned short*)carve((size_t)Bc*65536);   // h0 (bf16, Bc*32640B), then conv2 out
  unsigned short* buf2 = (unsigned short*)carve((size_t)Bc*65280);   // conv1 out
  unsigned short* Hcat = (unsigned short*)carve((size_t)Bc*33280);   // [Bc][16640] bf16
  float*          zp   = (float*)carve((size_t)Bc*8192);             // 2 x [Bc][1024]
  const int zoff = Bc*1024;

  hipLaunchKernelGGL(pack_w_bf16_kernel, dim3((128*64*3+255)/256), dim3(256), 0, stream, W1, W1b, 128, 64);
  hipLaunchKernelGGL(pack_w_bf16_kernel, dim3((256*128*3+255)/256), dim3(256), 0, stream, W2, W2b, 256, 128);
  hipLaunchKernelGGL(pack_w_bf16_kernel, dim3((256*256*3+255)/256), dim3(256), 0, stream, W3, W3b, 256, 256);
  hipLaunchKernelGGL(pack_wp_kernel, dim3(32), dim3(256), 0, stream, Wp, Bwp);
  hipLaunchKernelGGL(f2bf_kernel, dim3((17039360+255)/256), dim3(256), 0, stream, Wfc1, Wfc1b, 17039360);

  for (int c = 0; c < NC; ++c){
    const float* xc = x + (size_t)c*Bc*16384;
    hipLaunchKernelGGL(branch_kernel, dim3(Bc), dim3(256), 0, stream,
                       xc, Wb1, bb1, Wb2, bb2, Wb3, bb3, Hcat);
    hipLaunchKernelGGL(h0_gemm_kernel, dim3(Bc*255/128), dim3(256), 0, stream, xc, Bwp, bp, buf1);
    // conv1: 64->128, S=1, 255->255, BM=128 BN=128, 2 Mtiles x 1 Ntile
    hipLaunchKernelGGL((conv_gemm_kernel<64,128,1,255,255,128,128,2,false>), dim3(2, Bc), dim3(256), 0, stream,
                       buf1, W1b, b1, buf2);
    // conv2: 128->256, S=2, 255->128, BM=128 BN=128, 1 Mtile x 2 Ntiles
    hipLaunchKernelGGL((conv_gemm_kernel<128,256,2,255,128,128,128,2,false>), dim3(2, Bc), dim3(256), 0, stream,
                       buf2, W2b, b2, buf1);
    // conv3: 256->256, S=2, 128->64, BM=64 BN=256, 1x1, output channel-major into Hcat
    hipLaunchKernelGGL((conv_gemm_kernel<256,256,2,128,64,64,256,4,true>), dim3(1, Bc), dim3(256), 0, stream,
                       buf1, W3b, b3, Hcat);
    hipLaunchKernelGGL(fc1_gemm_kernel, dim3(8, Bc/128, 2), dim3(256), 0, stream, Hcat, Wfc1b, zp, zoff);
    hipLaunchKernelGGL(fc2_kernel, dim3(Bc), dim3(64), 0, stream, zp, zoff, bfc1, Wfc2, bfc2, out + (size_t)c*Bc*2);
  }
}

// Round 4
// 668.831 us; speedup vs baseline: 17.6239x; 1.1239x over previous
//
#include <hip/hip_runtime.h>
#include <cstdint>
#include <cstddef>

typedef __attribute__((ext_vector_type(8))) short bf16x8;
typedef __attribute__((ext_vector_type(8))) unsigned short ushort8;
typedef __attribute__((ext_vector_type(4))) float f32x4;

// round-to-nearest-even fp32 -> bf16 bits
__device__ __forceinline__ unsigned short f2bf(float f){
  unsigned int u = __float_as_uint(f);
  unsigned int lsb = (u >> 16) & 1u;
  u += 0x7fffu + lsb;
  return (unsigned short)(u >> 16);
}

// async global->LDS, 16B per lane; LDS dest = wave-uniform base + lane*16
__device__ __forceinline__ void gload16(const void* g, void* l){
  __builtin_amdgcn_global_load_lds(
      (const __attribute__((address_space(1))) unsigned int*)g,
      (__attribute__((address_space(3))) unsigned int*)l, 16, 0, 0);
}

// ---------------- weight packing ----------------
// conv weights (COUT,CIN,3) fp32 -> [o][kk][ci] bf16
__global__ __launch_bounds__(256) void pack_w_bf16_kernel(const float* __restrict__ W,
                                                          unsigned short* __restrict__ Wb,
                                                          int COUT, int CIN){
  int idx = blockIdx.x*256 + threadIdx.x;
  int tot = COUT*CIN*3;
  if (idx >= tot) return;
  int o = idx/(CIN*3); int r = idx - o*(CIN*3); int kk = r/CIN; int ci = r - kk*CIN;
  Wb[idx] = f2bf(W[(o*CIN + ci)*3 + kk]);
}

// h0 weights: Bw[p][k] bf16 ; k<64 -> Wp[p,k,0] ; k>=64 -> Wp[p,k-64,1]
__global__ __launch_bounds__(256) void pack_wp_kernel(const float* __restrict__ Wp,
                                                      unsigned short* __restrict__ Bw){
  int idx = blockIdx.x*256 + threadIdx.x;
  if (idx >= 64*128) return;
  int p = idx >> 7, k = idx & 127;
  float v = (k < 64) ? Wp[p*128 + k*2] : Wp[p*128 + (k-64)*2 + 1];
  Bw[idx] = f2bf(v);
}

__global__ __launch_bounds__(256) void f2bf_kernel(const float* __restrict__ src,
                                                   unsigned short* __restrict__ dst, int n){
  int i = blockIdx.x*256 + threadIdx.x;
  if (i < n) dst[i] = f2bf(src[i]);
}

// ---------------- branch MLP: x0 -> 64 -> 128 -> 256, writes f into Hcat[16384:] ----------------
__global__ __launch_bounds__(256) void branch_kernel(const float* __restrict__ x,
    const float* __restrict__ Wb1, const float* __restrict__ bb1,
    const float* __restrict__ Wb2, const float* __restrict__ bb2,
    const float* __restrict__ Wb3, const float* __restrict__ bb3,
    unsigned short* __restrict__ Hcat){
  __shared__ float s0[64], s1[64], s2[128];
  const int b = blockIdx.x, tid = threadIdx.x;
  const float* xb = x + (size_t)b*16384;
  if (tid < 64) s0[tid] = xb[tid];
  __syncthreads();
  if (tid < 64){
    float a = bb1[tid];
    for (int k=0;k<64;k++) a = fmaf(Wb1[tid*64+k], s0[k], a);
    s1[tid] = fmaxf(a, 0.f);
  }
  __syncthreads();
  if (tid < 128){
    float a = bb2[tid];
    for (int k=0;k<64;k++) a = fmaf(Wb2[tid*64+k], s1[k], a);
    s2[tid] = fmaxf(a, 0.f);
  }
  __syncthreads();
  float a = bb3[tid];
  for (int k=0;k<128;k++) a = fmaf(Wb3[tid*128+k], s2[k], a);
  Hcat[(size_t)b*16640 + 16384 + tid] = f2bf(fmaxf(a, 0.f));
}

// ---------------- h0 as MFMA GEMM: M=Bc*255 rows (b,pos), N=64 (p), K=128 ([x0|x_{pos+1}]) ----------------
__global__ __launch_bounds__(256) void h0_gemm_kernel(const float* __restrict__ x,
    const unsigned short* __restrict__ Bw, const float* __restrict__ bp,
    unsigned short* __restrict__ h0o){
  __shared__ __align__(16) char sAraw[128*256];
  __shared__ __align__(16) char sBraw[64*256];
  const int tid = threadIdx.x;
  const int m0 = blockIdx.x*128;
  #pragma unroll
  for (int i=0;i<16;i++){
    int j = tid + 256*i;
    int row = j >> 5, q = j & 31;
    int m = m0 + row;
    int b = m / 255, c = m - b*255;
    const float* xb = x + (size_t)b*16384;
    int k = q*4;
    const float* src = (k < 64) ? (xb + k) : (xb + (c+1)*64 + (k-64));
    float4 v = *(const float4*)src;
    ushort4 u; u.x=f2bf(v.x); u.y=f2bf(v.y); u.z=f2bf(v.z); u.w=f2bf(v.w);
    *(ushort4*)(sAraw + row*256 + ((k*2) ^ ((row&7)<<4))) = u;
  }
  #pragma unroll
  for (int i=0;i<4;i++){
    int j = tid + 256*i;
    int row = j >> 4, q = j & 15;
    int k = q*8;
    ushort8 u = *(const ushort8*)(Bw + row*128 + k);
    *(ushort8*)(sBraw + row*256 + ((k*2) ^ ((row&7)<<4))) = u;
  }
  __syncthreads();
  const int lane = tid & 63, wid = tid >> 6;
  const int lr = lane & 15, lg = lane >> 4;
  f32x4 zero = {0.f,0.f,0.f,0.f};
  f32x4 acc[2][4];
  #pragma unroll
  for (int a=0;a<2;a++){ acc[a][0]=zero; acc[a][1]=zero; acc[a][2]=zero; acc[a][3]=zero; }
  #pragma unroll
  for (int ks=0; ks<4; ks++){
    int k = ks*32 + lg*8;
    bf16x8 af[2], bfr[4];
    #pragma unroll
    for (int f=0; f<2; f++){
      int row = wid*32 + f*16 + lr;
      af[f] = *(const bf16x8*)(sAraw + row*256 + ((k*2) ^ ((row&7)<<4)));
    }
    #pragma unroll
    for (int f=0; f<4; f++){
      int row = f*16 + lr;
      bfr[f] = *(const bf16x8*)(sBraw + row*256 + ((k*2) ^ ((row&7)<<4)));
    }
    #pragma unroll
    for (int fi=0; fi<2; fi++)
      #pragma unroll
      for (int fj=0; fj<4; fj++)
        acc[fi][fj] = __builtin_amdgcn_mfma_f32_16x16x32_bf16(af[fi], bfr[fj], acc[fi][fj], 0,0,0);
  }
  #pragma unroll
  for (int fi=0; fi<2; fi++)
    #pragma unroll
    for (int fj=0; fj<4; fj++)
      #pragma unroll
      for (int j=0;j<4;j++){
        int m = m0 + wid*32 + fi*16 + lg*4 + j;
        int n = fj*16 + lr;
        h0o[(size_t)m*64 + n] = f2bf(fmaxf(acc[fi][fj][j] + bp[n], 0.f));
      }
}

// ---------------- implicit-GEMM bf16 conv1d (k=3,pad=1) + relu ----------------
template<int CIN,int COUT,int S,int LIN,int LOUT,int BM,int BN,int WN,bool TO_HCAT>
__global__ __launch_bounds__(256) void conv_gemm_kernel(
    const unsigned short* __restrict__ in, const unsigned short* __restrict__ Wb,
    const float* __restrict__ bias, unsigned short* __restrict__ out){
  constexpr int MT = (LOUT + BM - 1)/BM;
  __shared__ __align__(16) char sA[BM*128];
  __shared__ __align__(16) char sB[BN*128];
  const int tid = threadIdx.x;
  const int b  = blockIdx.y;
  const int mt = blockIdx.x % MT;
  const int nt = blockIdx.x / MT;
  const int m0 = mt*BM, n0 = nt*BN;
  const unsigned short* inb = in + (size_t)b*LIN*CIN;
  const int lane = tid & 63, wid = tid >> 6;
  const int wm = wid / WN, wn = wid % WN;
  const int lr = lane & 15, lg = lane >> 4;
  f32x4 zero = {0.f,0.f,0.f,0.f};
  f32x4 acc[4][4];
  #pragma unroll
  for (int i=0;i<4;i++){ acc[i][0]=zero; acc[i][1]=zero; acc[i][2]=zero; acc[i][3]=zero; }
  #pragma unroll
  for (int kk=0; kk<3; kk++){
    #pragma unroll
    for (int cc=0; cc<CIN/64; cc++){
      __syncthreads();
      #pragma unroll
      for (int p=0; p<BM/32; p++){
        int slot = tid + p*256;
        int row = slot >> 3, c8 = slot & 7;
        int pos = (m0 + row)*S - 1 + kk;
        ushort8 v = {0,0,0,0,0,0,0,0};
        if (pos >= 0 && pos < LIN)
          v = *(const ushort8*)(inb + (size_t)pos*CIN + cc*64 + c8*8);
        *(ushort8*)(sA + row*128 + ((c8*16) ^ ((row&7)<<4))) = v;
      }
      #pragma unroll
      for (int p=0; p<BN/32; p++){
        int slot = tid + p*256;
        int row = slot >> 3, c8 = slot & 7;
        ushort8 v = *(const ushort8*)(Wb + ((size_t)(n0+row)*3 + kk)*CIN + cc*64 + c8*8);
        *(ushort8*)(sB + row*128 + ((c8*16) ^ ((row&7)<<4))) = v;
      }
      __syncthreads();
      #pragma unroll
      for (int ks=0; ks<2; ks++){
        const int k = ks*32 + lg*8;
        bf16x8 af[4], bf[4];
        #pragma unroll
        for (int f=0;f<4;f++){
          int ra = wm*64 + f*16 + lr;
          af[f] = *(const bf16x8*)(sA + ra*128 + ((k*2) ^ ((ra&7)<<4)));
          int rb = wn*64 + f*16 + lr;
          bf[f] = *(const bf16x8*)(sB + rb*128 + ((k*2) ^ ((rb&7)<<4)));
        }
        #pragma unroll
        for (int fi=0;fi<4;fi++)
          #pragma unroll
          for (int fj=0;fj<4;fj++)
            acc[fi][fj] = __builtin_amdgcn_mfma_f32_16x16x32_bf16(af[fi], bf[fj], acc[fi][fj], 0,0,0);
      }
    }
  }
  unsigned short* outb = TO_HCAT ? (out + (size_t)b*16640) : (out + (size_t)b*LOUT*COUT);
  #pragma unroll
  for (int fi=0;fi<4;fi++)
    #pragma unroll
    for (int fj=0;fj<4;fj++)
      #pragma unroll
      for (int j=0;j<4;j++){
        int m = m0 + wm*64 + fi*16 + lg*4 + j;
        int n = n0 + wn*64 + fj*16 + lr;
        if (m < LOUT){
          float val = fmaxf(acc[fi][fj][j] + bias[n], 0.f);
          if (TO_HCAT) outb[(size_t)n*64 + m] = f2bf(val);
          else         outb[(size_t)m*COUT + n] = f2bf(val);
        }
      }
}

// ---------------- fc1: bf16 MFMA GEMM, M=Bc, N=1024, K=16640=260*64, K-split KZ ----------------
// grid = 8*MT*KZ blocks; XCD-bijective swizzle groups all tiles of one kz per XCD.
// global_load_lds staging: linear LDS dest, inverse-swizzled per-lane global source.
__global__ __launch_bounds__(256) void fc1_gemm_kernel(
    const unsigned short* __restrict__ A, const unsigned short* __restrict__ Bw,
    float* __restrict__ zp, int zoffm, int MT, int KZ){
  __shared__ __align__(16) char sA[128*128];   // 128 rows x 64 bf16, swizzled slot = chunk ^ (row&7)
  __shared__ __align__(16) char sB[128*128];
  const int tid = threadIdx.x;
  const int nwg = gridDim.x;                   // multiple of 8
  const int lgid = (blockIdx.x % 8)*(nwg/8) + blockIdx.x/8;   // XCD-chunked
  const int kz  = lgid / (8*MT);
  const int rem = lgid % (8*MT);
  const int nt  = rem / MT;
  const int mt  = rem % MT;
  const int n0 = nt*128, m0 = mt*128;
  const int lane = tid & 63, wid = tid >> 6;
  const int wm = wid >> 1, wn = wid & 1;
  const int lr = lane & 15, lg = lane >> 4;
  // staging source: lane l covers row (base + l>>3), logical chunk (l&7)^(l>>3)
  const int srow = lane >> 3;
  const int soff = (((lane&7) ^ srow) << 3);   // element offset within 64
  f32x4 zero = {0.f,0.f,0.f,0.f};
  f32x4 acc[4][4];
  #pragma unroll
  for (int i=0;i<4;i++){ acc[i][0]=zero; acc[i][1]=zero; acc[i][2]=zero; acc[i][3]=zero; }
  const int it0 = (kz*260)/KZ, it1 = ((kz+1)*260)/KZ;
  for (int it=it0; it<it1; ++it){
    const size_t k0 = (size_t)it*64;
    __syncthreads();
    #pragma unroll
    for (int s=0;s<4;s++){
      int row = wid*32 + s*8 + srow;
      gload16(A  + (size_t)(m0+row)*16640 + k0 + soff, sA + wid*4096 + s*1024);
      gload16(Bw + (size_t)(n0+row)*16640 + k0 + soff, sB + wid*4096 + s*1024);
    }
    __syncthreads();   // compiler drains vmcnt(0) before barrier -> LDS ready
    #pragma unroll
    for (int ks=0; ks<2; ks++){
      const int k = ks*32 + lg*8;
      bf16x8 af[4], bfr[4];
      #pragma unroll
      for (int f=0;f<4;f++){
        int rowa = wm*64 + f*16 + lr;
        af[f]  = *(const bf16x8*)(sA + rowa*128 + ((k*2) ^ ((rowa&7)<<4)));
        int rowb = wn*64 + f*16 + lr;
        bfr[f] = *(const bf16x8*)(sB + rowb*128 + ((k*2) ^ ((rowb&7)<<4)));
      }
      #pragma unroll
      for (int fi=0;fi<4;fi++)
        #pragma unroll
        for (int fj=0;fj<4;fj++)
          acc[fi][fj] = __builtin_amdgcn_mfma_f32_16x16x32_bf16(af[fi], bfr[fj], acc[fi][fj], 0,0,0);
    }
  }
  float* zo = zp + (size_t)kz*zoffm;
  #pragma unroll
  for (int fi=0;fi<4;fi++)
    #pragma unroll
    for (int fj=0;fj<4;fj++)
      #pragma unroll
      for (int j=0;j<4;j++){
        int m = m0 + wm*64 + fi*16 + lg*4 + j;
        int n = n0 + wn*64 + fj*16 + lr;
        zo[(size_t)m*1024 + n] = acc[fi][fj][j];
      }
}

// ---------------- fc2: combine KZ partials, bias+relu, then 1024->2 ----------------
__global__ __launch_bounds__(256) void fc2_kernel(const float* __restrict__ zp, int zoffm, int KZ,
    const float* __restrict__ bfc1, const float* __restrict__ Wfc2,
    const float* __restrict__ bfc2, float* __restrict__ out){
  __shared__ float red[4][2];
  const int b = blockIdx.x, tid = threadIdx.x;
  float a0 = 0.f, a1 = 0.f;
  for (int n = tid; n < 1024; n += 256){
    float s = bfc1[n];
    const float* zb = zp + (size_t)b*1024 + n;
    for (int kz = 0; kz < KZ; kz++) s += zb[(size_t)kz*zoffm];
    s = fmaxf(s, 0.f);
    a0 = fmaf(s, Wfc2[n], a0);
    a1 = fmaf(s, Wfc2[1024+n], a1);
  }
  #pragma unroll
  for (int m=32; m>=1; m>>=1){ a0 += __shfl_xor(a0, m, 64); a1 += __shfl_xor(a1, m, 64); }
  const int w = tid >> 6;
  if ((tid & 63) == 0){ red[w][0] = a0; red[w][1] = a1; }
  __syncthreads();
  if (tid == 0){
    float s0 = red[0][0]+red[1][0]+red[2][0]+red[3][0];
    float s1 = red[0][1]+red[1][1]+red[2][1]+red[3][1];
    out[(size_t)b*2]   = s0 + bfc2[0];
    out[(size_t)b*2+1] = s1 + bfc2[1];
  }
}

extern "C" void kernel_launch(void* const* d_in, const int* in_sizes, int n_in,
                              void* d_out, int out_size, void* d_ws, size_t ws_size,
                              hipStream_t stream){
  const float* x    = (const float*)d_in[0];
  const float* Wp   = (const float*)d_in[1];
  const float* bp   = (const float*)d_in[2];
  const float* W1   = (const float*)d_in[3];
  const float* b1   = (const float*)d_in[4];
  const float* W2   = (const float*)d_in[5];
  const float* b2   = (const float*)d_in[6];
  const float* W3   = (const float*)d_in[7];
  const float* b3   = (const float*)d_in[8];
  const float* Wb1  = (const float*)d_in[9];
  const float* bb1  = (const float*)d_in[10];
  const float* Wb2  = (const float*)d_in[11];
  const float* bb2  = (const float*)d_in[12];
  const float* Wb3  = (const float*)d_in[13];
  const float* bb3  = (const float*)d_in[14];
  const float* Wfc1 = (const float*)d_in[15];
  const float* bfc1 = (const float*)d_in[16];
  const float* Wfc2 = (const float*)d_in[17];
  const float* bfc2 = (const float*)d_in[18];
  float* out = (float*)d_out;

  size_t off = 0;
  char* basep = (char*)d_ws;
  auto carve = [&](size_t bytes)->char*{
    char* q = basep + off; off += (bytes + 255) & ~(size_t)255; return q;
  };
  unsigned short* W1b   = (unsigned short*)carve((size_t)128*3*64*2);
  unsigned short* W2b   = (unsigned short*)carve((size_t)256*3*128*2);
  unsigned short* W3b   = (unsigned short*)carve((size_t)256*3*256*2);
  unsigned short* Bwp   = (unsigned short*)carve((size_t)64*128*2);
  unsigned short* Wfc1b = (unsigned short*)carve((size_t)1024*16640*2);
  size_t fixed = off;

  // pick largest Bc that fits; KZ chosen so fc1 grid = 8*(Bc/128)*KZ = 512 blocks (2/CU)
  int Bc = 128, KZ = 64;
  {
    const int bcs[5] = {2048, 1024, 512, 256, 128};
    const int kzs[5] = {4, 8, 16, 32, 64};
    for (int i = 0; i < 5; i++){
      size_t b = bcs[i];
      size_t need = fixed + b*((size_t)65536+65280+33280) + (size_t)kzs[i]*b*4096 + 16*256;
      if (need <= ws_size){ Bc = bcs[i]; KZ = kzs[i]; break; }
    }
  }
  const int NC = 2048/Bc;
  const int MT = Bc/128;
  unsigned short* buf1 = (unsigned short*)carve((size_t)Bc*65536);   // h0 bf16, then conv2 out
  unsigned short* buf2 = (unsigned short*)carve((size_t)Bc*65280);   // conv1 out
  unsigned short* Hcat = (unsigned short*)carve((size_t)Bc*33280);   // [Bc][16640] bf16
  float*          zp   = (float*)carve((size_t)KZ*Bc*4096);          // KZ x [Bc][1024] fp32
  const int zoffm = Bc*1024;

  hipLaunchKernelGGL(pack_w_bf16_kernel, dim3((128*64*3+255)/256), dim3(256), 0, stream, W1, W1b, 128, 64);
  hipLaunchKernelGGL(pack_w_bf16_kernel, dim3((256*128*3+255)/256), dim3(256), 0, stream, W2, W2b, 256, 128);
  hipLaunchKernelGGL(pack_w_bf16_kernel, dim3((256*256*3+255)/256), dim3(256), 0, stream, W3, W3b, 256, 256);
  hipLaunchKernelGGL(pack_wp_kernel, dim3(32), dim3(256), 0, stream, Wp, Bwp);
  hipLaunchKernelGGL(f2bf_kernel, dim3((17039360+255)/256), dim3(256), 0, stream, Wfc1, Wfc1b, 17039360);

  for (int c = 0; c < NC; ++c){
    const float* xc = x + (size_t)c*Bc*16384;
    hipLaunchKernelGGL(branch_kernel, dim3(Bc), dim3(256), 0, stream,
                       xc, Wb1, bb1, Wb2, bb2, Wb3, bb3, Hcat);
    hipLaunchKernelGGL(h0_gemm_kernel, dim3(Bc*255/128), dim3(256), 0, stream, xc, Bwp, bp, buf1);
    hipLaunchKernelGGL((conv_gemm_kernel<64,128,1,255,255,128,128,2,false>), dim3(2, Bc), dim3(256), 0, stream,
                       buf1, W1b, b1, buf2);
    hipLaunchKernelGGL((conv_gemm_kernel<128,256,2,255,128,128,128,2,false>), dim3(2, Bc), dim3(256), 0, stream,
                       buf2, W2b, b2, buf1);
    hipLaunchKernelGGL((conv_gemm_kernel<256,256,2,128,64,64,256,4,true>), dim3(1, Bc), dim3(256), 0, stream,
                       buf1, W3b, b3, Hcat);
    hipLaunchKernelGGL(fc1_gemm_kernel, dim3(8*MT*KZ), dim3(256), 0, stream,
                       Hcat, Wfc1b, zp, zoffm, MT, KZ);
    hipLaunchKernelGGL(fc2_kernel, dim3(Bc), dim3(256), 0, stream,
                       zp, zoffm, KZ, bfc1, Wfc2, bfc2, out + (size_t)c*Bc*2);
  }
}

// Round 5
// 554.793 us; speedup vs baseline: 21.2465x; 1.2056x over previous
//
#include <hip/hip_runtime.h>
#include <cstdint>
#include <cstddef>

typedef __attribute__((ext_vector_type(8))) short bf16x8;
typedef __attribute__((ext_vector_type(8))) unsigned short ushort8;
typedef __attribute__((ext_vector_type(4))) float f32x4;

// round-to-nearest-even fp32 -> bf16 bits
__device__ __forceinline__ unsigned short f2bf(float f){
  unsigned int u = __float_as_uint(f);
  unsigned int lsb = (u >> 16) & 1u;
  u += 0x7fffu + lsb;
  return (unsigned short)(u >> 16);
}

// async global->LDS, 16B per lane; LDS dest = wave-uniform base + lane*16
__device__ __forceinline__ void gload16(const void* g, void* l){
  __builtin_amdgcn_global_load_lds(
      (const __attribute__((address_space(1))) unsigned int*)g,
      (__attribute__((address_space(3))) unsigned int*)l, 16, 0, 0);
}

// ---------------- weight packing ----------------
// conv weights (COUT,CIN,3) fp32 -> [o][kk][ci] bf16  (== [o][3*CIN] im2col-major)
__global__ __launch_bounds__(256) void pack_w_bf16_kernel(const float* __restrict__ W,
                                                          unsigned short* __restrict__ Wb,
                                                          int COUT, int CIN){
  int idx = blockIdx.x*256 + threadIdx.x;
  int tot = COUT*CIN*3;
  if (idx >= tot) return;
  int o = idx/(CIN*3); int r = idx - o*(CIN*3); int kk = r/CIN; int ci = r - kk*CIN;
  Wb[idx] = f2bf(W[(o*CIN + ci)*3 + kk]);
}

// h0 weights: Bw[p][k] bf16 ; k<64 -> Wp[p,k,0] ; k>=64 -> Wp[p,k-64,1]
__global__ __launch_bounds__(256) void pack_wp_kernel(const float* __restrict__ Wp,
                                                      unsigned short* __restrict__ Bw){
  int idx = blockIdx.x*256 + threadIdx.x;
  if (idx >= 64*128) return;
  int p = idx >> 7, k = idx & 127;
  float v = (k < 64) ? Wp[p*128 + k*2] : Wp[p*128 + (k-64)*2 + 1];
  Bw[idx] = f2bf(v);
}

__global__ __launch_bounds__(256) void f2bf_kernel(const float* __restrict__ src,
                                                   unsigned short* __restrict__ dst, int n){
  int i = blockIdx.x*256 + threadIdx.x;
  if (i < n) dst[i] = f2bf(src[i]);
}

// zero the two guard rows (row 0 and row LINP-1) of each batch's padded region
__global__ __launch_bounds__(256) void zero_guards_kernel(unsigned short* __restrict__ buf,
                                                          int LINP, int CIN, int nb){
  int idx = blockIdx.x*256 + threadIdx.x;           // one ushort8 per thread
  int per = 2*CIN/8;
  if (idx >= nb*per) return;
  int b = idx / per, r = idx - b*per;
  int g = r / (CIN/8), c8 = r - g*(CIN/8);
  ushort8 z = {0,0,0,0,0,0,0,0};
  *(ushort8*)(buf + ((size_t)b*LINP + (size_t)g*(LINP-1))*CIN + c8*8) = z;
}

// ---------------- branch MLP: x0 -> 64 -> 128 -> 256, writes f into Hcat[16384:] ----------------
__global__ __launch_bounds__(256) void branch_kernel(const float* __restrict__ x,
    const float* __restrict__ Wb1, const float* __restrict__ bb1,
    const float* __restrict__ Wb2, const float* __restrict__ bb2,
    const float* __restrict__ Wb3, const float* __restrict__ bb3,
    unsigned short* __restrict__ Hcat){
  __shared__ float s0[64], s1[64], s2[128];
  const int b = blockIdx.x, tid = threadIdx.x;
  const float* xb = x + (size_t)b*16384;
  if (tid < 64) s0[tid] = xb[tid];
  __syncthreads();
  if (tid < 64){
    float a = bb1[tid];
    for (int k=0;k<64;k++) a = fmaf(Wb1[tid*64+k], s0[k], a);
    s1[tid] = fmaxf(a, 0.f);
  }
  __syncthreads();
  if (tid < 128){
    float a = bb2[tid];
    for (int k=0;k<64;k++) a = fmaf(Wb2[tid*64+k], s1[k], a);
    s2[tid] = fmaxf(a, 0.f);
  }
  __syncthreads();
  float a = bb3[tid];
  for (int k=0;k<128;k++) a = fmaf(Wb3[tid*128+k], s2[k], a);
  Hcat[(size_t)b*16640 + 16384 + tid] = f2bf(fmaxf(a, 0.f));
}

// ---------------- h0 as MFMA GEMM: M=Bc*255 rows (b,pos), N=64 (p), K=128 ([x0|x_{pos+1}]) ----------------
// output: padded bf16 [b][257][64], data rows 1..255
__global__ __launch_bounds__(256) void h0_gemm_kernel(const float* __restrict__ x,
    const unsigned short* __restrict__ Bw, const float* __restrict__ bp,
    unsigned short* __restrict__ h0o){
  __shared__ __align__(16) char sAraw[128*256];
  __shared__ __align__(16) char sBraw[64*256];
  const int tid = threadIdx.x;
  const int m0 = blockIdx.x*128;
  #pragma unroll
  for (int i=0;i<16;i++){
    int j = tid + 256*i;
    int row = j >> 5, q = j & 31;
    int m = m0 + row;
    int b = m / 255, c = m - b*255;
    const float* xb = x + (size_t)b*16384;
    int k = q*4;
    const float* src = (k < 64) ? (xb + k) : (xb + (c+1)*64 + (k-64));
    float4 v = *(const float4*)src;
    ushort4 u; u.x=f2bf(v.x); u.y=f2bf(v.y); u.z=f2bf(v.z); u.w=f2bf(v.w);
    *(ushort4*)(sAraw + row*256 + ((k*2) ^ ((row&7)<<4))) = u;
  }
  #pragma unroll
  for (int i=0;i<4;i++){
    int j = tid + 256*i;
    int row = j >> 4, q = j & 15;
    int k = q*8;
    ushort8 u = *(const ushort8*)(Bw + row*128 + k);
    *(ushort8*)(sBraw + row*256 + ((k*2) ^ ((row&7)<<4))) = u;
  }
  __syncthreads();
  const int lane = tid & 63, wid = tid >> 6;
  const int lr = lane & 15, lg = lane >> 4;
  f32x4 zero = {0.f,0.f,0.f,0.f};
  f32x4 acc[2][4];
  #pragma unroll
  for (int a=0;a<2;a++){ acc[a][0]=zero; acc[a][1]=zero; acc[a][2]=zero; acc[a][3]=zero; }
  #pragma unroll
  for (int ks=0; ks<4; ks++){
    int k = ks*32 + lg*8;
    bf16x8 af[2], bfr[4];
    #pragma unroll
    for (int f=0; f<2; f++){
      int row = wid*32 + f*16 + lr;
      af[f] = *(const bf16x8*)(sAraw + row*256 + ((k*2) ^ ((row&7)<<4)));
    }
    #pragma unroll
    for (int f=0; f<4; f++){
      int row = f*16 + lr;
      bfr[f] = *(const bf16x8*)(sBraw + row*256 + ((k*2) ^ ((row&7)<<4)));
    }
    #pragma unroll
    for (int fi=0; fi<2; fi++)
      #pragma unroll
      for (int fj=0; fj<4; fj++)
        acc[fi][fj] = __builtin_amdgcn_mfma_f32_16x16x32_bf16(af[fi], bfr[fj], acc[fi][fj], 0,0,0);
  }
  #pragma unroll
  for (int fi=0; fi<2; fi++)
    #pragma unroll
    for (int fj=0; fj<4; fj++)
      #pragma unroll
      for (int j=0;j<4;j++){
        int m = m0 + wid*32 + fi*16 + lg*4 + j;
        int n = fj*16 + lr;
        int b = m / 255, t = m - b*255;
        h0o[((size_t)b*257 + t + 1)*64 + n] = f2bf(fmaxf(acc[fi][fj][j] + bp[n], 0.f));
      }
}

// ---------------- conv1d as plain GEMM over padded activations ----------------
// in: bf16 padded [b][LINP][CIN] (data at rows 1..LINP-2, guards zero)
// A row m=(b,t): contiguous 3*CIN slice starting at padded row t*S
// Wb: bf16 [COUT][3*CIN] ; out: padded [b][LOUT+2][COUT] at row t+1, or Hcat channel-major
template<int CIN,int COUT,int S,int LINP,int LOUT,bool TO_HCAT>
__global__ __launch_bounds__(256) void conv_gemm_kernel(
    const unsigned short* __restrict__ in, const unsigned short* __restrict__ Wb,
    const float* __restrict__ bias, unsigned short* __restrict__ out){
  constexpr int K = 3*CIN;
  constexpr int KS = K/64;
  __shared__ __align__(16) char sA[128*128];   // 128 rows x 64 bf16, slot = chunk ^ (row&7)
  __shared__ __align__(16) char sB[128*128];
  const int tid = threadIdx.x;
  const int m0 = blockIdx.x*128;
  const int n0 = blockIdx.y*128;
  const int lane = tid & 63, wid = tid >> 6;
  const int wm = wid >> 1, wn = wid & 1;
  const int lr = lane & 15, lg = lane >> 4;
  const int srow = lane >> 3;
  const int soff = (((lane&7) ^ srow) << 3);
  // hoist per-lane staging base addresses
  const unsigned short* abase[4];
  const unsigned short* bbase[4];
  #pragma unroll
  for (int s=0;s<4;s++){
    int row = wid*32 + s*8 + srow;
    int m = m0 + row;
    int b = m / LOUT, t = m - b*LOUT;
    abase[s] = in + ((size_t)b*LINP + (size_t)t*S)*CIN + soff;
    bbase[s] = Wb + (size_t)(n0+row)*K + soff;
  }
  f32x4 zero = {0.f,0.f,0.f,0.f};
  f32x4 acc[4][4];
  #pragma unroll
  for (int i=0;i<4;i++){ acc[i][0]=zero; acc[i][1]=zero; acc[i][2]=zero; acc[i][3]=zero; }
  for (int ks=0; ks<KS; ks++){
    const int k0 = ks*64;
    __syncthreads();
    #pragma unroll
    for (int s=0;s<4;s++){
      gload16(abase[s] + k0, sA + wid*4096 + s*1024);
      gload16(bbase[s] + k0, sB + wid*4096 + s*1024);
    }
    __syncthreads();
    #pragma unroll
    for (int kss=0; kss<2; kss++){
      const int k = kss*32 + lg*8;
      bf16x8 af[4], bfr[4];
      #pragma unroll
      for (int f=0;f<4;f++){
        int ra = wm*64 + f*16 + lr;
        af[f]  = *(const bf16x8*)(sA + ra*128 + ((k*2) ^ ((ra&7)<<4)));
        int rb = wn*64 + f*16 + lr;
        bfr[f] = *(const bf16x8*)(sB + rb*128 + ((k*2) ^ ((rb&7)<<4)));
      }
      #pragma unroll
      for (int fi=0;fi<4;fi++)
        #pragma unroll
        for (int fj=0;fj<4;fj++)
          acc[fi][fj] = __builtin_amdgcn_mfma_f32_16x16x32_bf16(af[fi], bfr[fj], acc[fi][fj], 0,0,0);
    }
  }
  #pragma unroll
  for (int fi=0;fi<4;fi++)
    #pragma unroll
    for (int fj=0;fj<4;fj++)
      #pragma unroll
      for (int j=0;j<4;j++){
        int m = m0 + wm*64 + fi*16 + lg*4 + j;
        int n = n0 + wn*64 + fj*16 + lr;
        int b = m / LOUT, t = m - b*LOUT;
        float val = fmaxf(acc[fi][fj][j] + bias[n], 0.f);
        if (TO_HCAT) out[(size_t)b*16640 + (size_t)n*64 + t] = f2bf(val);
        else         out[((size_t)b*(LOUT+2) + t + 1)*COUT + n] = f2bf(val);
      }
}

// ---------------- fc1: bf16 MFMA GEMM, M=Bc, N=1024, K=16640=260*64, K-split KZ ----------------
__global__ __launch_bounds__(256) void fc1_gemm_kernel(
    const unsigned short* __restrict__ A, const unsigned short* __restrict__ Bw,
    float* __restrict__ zp, int zoffm, int MT, int KZ){
  __shared__ __align__(16) char sA[128*128];
  __shared__ __align__(16) char sB[128*128];
  const int tid = threadIdx.x;
  const int nwg = gridDim.x;
  const int lgid = (blockIdx.x % 8)*(nwg/8) + blockIdx.x/8;
  const int kz  = lgid / (8*MT);
  const int rem = lgid % (8*MT);
  const int nt  = rem / MT;
  const int mt  = rem % MT;
  const int n0 = nt*128, m0 = mt*128;
  const int lane = tid & 63, wid = tid >> 6;
  const int wm = wid >> 1, wn = wid & 1;
  const int lr = lane & 15, lg = lane >> 4;
  const int srow = lane >> 3;
  const int soff = (((lane&7) ^ srow) << 3);
  f32x4 zero = {0.f,0.f,0.f,0.f};
  f32x4 acc[4][4];
  #pragma unroll
  for (int i=0;i<4;i++){ acc[i][0]=zero; acc[i][1]=zero; acc[i][2]=zero; acc[i][3]=zero; }
  const int it0 = (kz*260)/KZ, it1 = ((kz+1)*260)/KZ;
  for (int it=it0; it<it1; ++it){
    const size_t k0 = (size_t)it*64;
    __syncthreads();
    #pragma unroll
    for (int s=0;s<4;s++){
      int row = wid*32 + s*8 + srow;
      gload16(A  + (size_t)(m0+row)*16640 + k0 + soff, sA + wid*4096 + s*1024);
      gload16(Bw + (size_t)(n0+row)*16640 + k0 + soff, sB + wid*4096 + s*1024);
    }
    __syncthreads();
    #pragma unroll
    for (int ks=0; ks<2; ks++){
      const int k = ks*32 + lg*8;
      bf16x8 af[4], bfr[4];
      #pragma unroll
      for (int f=0;f<4;f++){
        int rowa = wm*64 + f*16 + lr;
        af[f]  = *(const bf16x8*)(sA + rowa*128 + ((k*2) ^ ((rowa&7)<<4)));
        int rowb = wn*64 + f*16 + lr;
        bfr[f] = *(const bf16x8*)(sB + rowb*128 + ((k*2) ^ ((rowb&7)<<4)));
      }
      #pragma unroll
      for (int fi=0;fi<4;fi++)
        #pragma unroll
        for (int fj=0;fj<4;fj++)
          acc[fi][fj] = __builtin_amdgcn_mfma_f32_16x16x32_bf16(af[fi], bfr[fj], acc[fi][fj], 0,0,0);
    }
  }
  float* zo = zp + (size_t)kz*zoffm;
  #pragma unroll
  for (int fi=0;fi<4;fi++)
    #pragma unroll
    for (int fj=0;fj<4;fj++)
      #pragma unroll
      for (int j=0;j<4;j++){
        int m = m0 + wm*64 + fi*16 + lg*4 + j;
        int n = n0 + wn*64 + fj*16 + lr;
        zo[(size_t)m*1024 + n] = acc[fi][fj][j];
      }
}

// ---------------- fc2: combine KZ partials, bias+relu, then 1024->2 ----------------
__global__ __launch_bounds__(256) void fc2_kernel(const float* __restrict__ zp, int zoffm, int KZ,
    const float* __restrict__ bfc1, const float* __restrict__ Wfc2,
    const float* __restrict__ bfc2, float* __restrict__ out){
  __shared__ float red[4][2];
  const int b = blockIdx.x, tid = threadIdx.x;
  float a0 = 0.f, a1 = 0.f;
  for (int n = tid; n < 1024; n += 256){
    float s = bfc1[n];
    const float* zb = zp + (size_t)b*1024 + n;
    for (int kz = 0; kz < KZ; kz++) s += zb[(size_t)kz*zoffm];
    s = fmaxf(s, 0.f);
    a0 = fmaf(s, Wfc2[n], a0);
    a1 = fmaf(s, Wfc2[1024+n], a1);
  }
  #pragma unroll
  for (int m=32; m>=1; m>>=1){ a0 += __shfl_xor(a0, m, 64); a1 += __shfl_xor(a1, m, 64); }
  const int w = tid >> 6;
  if ((tid & 63) == 0){ red[w][0] = a0; red[w][1] = a1; }
  __syncthreads();
  if (tid == 0){
    float s0 = red[0][0]+red[1][0]+red[2][0]+red[3][0];
    float s1 = red[0][1]+red[1][1]+red[2][1]+red[3][1];
    out[(size_t)b*2]   = s0 + bfc2[0];
    out[(size_t)b*2+1] = s1 + bfc2[1];
  }
}

extern "C" void kernel_launch(void* const* d_in, const int* in_sizes, int n_in,
                              void* d_out, int out_size, void* d_ws, size_t ws_size,
                              hipStream_t stream){
  const float* x    = (const float*)d_in[0];
  const float* Wp   = (const float*)d_in[1];
  const float* bp   = (const float*)d_in[2];
  const float* W1   = (const float*)d_in[3];
  const float* b1   = (const float*)d_in[4];
  const float* W2   = (const float*)d_in[5];
  const float* b2   = (const float*)d_in[6];
  const float* W3   = (const float*)d_in[7];
  const float* b3   = (const float*)d_in[8];
  const float* Wb1  = (const float*)d_in[9];
  const float* bb1  = (const float*)d_in[10];
  const float* Wb2  = (const float*)d_in[11];
  const float* bb2  = (const float*)d_in[12];
  const float* Wb3  = (const float*)d_in[13];
  const float* bb3  = (const float*)d_in[14];
  const float* Wfc1 = (const float*)d_in[15];
  const float* bfc1 = (const float*)d_in[16];
  const float* Wfc2 = (const float*)d_in[17];
  const float* bfc2 = (const float*)d_in[18];
  float* out = (float*)d_out;

  size_t off = 0;
  char* basep = (char*)d_ws;
  auto carve = [&](size_t bytes)->char*{
    char* q = basep + off; off += (bytes + 255) & ~(size_t)255; return q;
  };
  unsigned short* W1b   = (unsigned short*)carve((size_t)128*3*64*2);
  unsigned short* W2b   = (unsigned short*)carve((size_t)256*3*128*2);
  unsigned short* W3b   = (unsigned short*)carve((size_t)256*3*256*2);
  unsigned short* Bwp   = (unsigned short*)carve((size_t)64*128*2);
  unsigned short* Wfc1b = (unsigned short*)carve((size_t)1024*16640*2);
  size_t fixed = off;

  // per-chunk: buf1 = max(h0 padded 257*64, conv2out padded 130*256) = 33280 el
  //            buf2 = conv1out padded 257*128 = 32896 el ; Hcat 16640 el ; zp KZ*1024 f32
  int Bc = 128, KZ = 64;
  {
    const int bcs[5] = {2048, 1024, 512, 256, 128};
    const int kzs[5] = {4, 8, 16, 32, 64};
    for (int i = 0; i < 5; i++){
      size_t b = bcs[i];
      size_t need = fixed + b*((size_t)66560+65792+33280) + (size_t)kzs[i]*b*4096 + 16*256;
      if (need <= ws_size){ Bc = bcs[i]; KZ = kzs[i]; break; }
    }
  }
  const int NC = 2048/Bc;
  const int MT = Bc/128;
  unsigned short* buf1 = (unsigned short*)carve((size_t)Bc*66560);
  unsigned short* buf2 = (unsigned short*)carve((size_t)Bc*65792);
  unsigned short* Hcat = (unsigned short*)carve((size_t)Bc*33280);
  float*          zp   = (float*)carve((size_t)KZ*Bc*4096);
  const int zoffm = Bc*1024;

  hipLaunchKernelGGL(pack_w_bf16_kernel, dim3((128*64*3+255)/256), dim3(256), 0, stream, W1, W1b, 128, 64);
  hipLaunchKernelGGL(pack_w_bf16_kernel, dim3((256*128*3+255)/256), dim3(256), 0, stream, W2, W2b, 256, 128);
  hipLaunchKernelGGL(pack_w_bf16_kernel, dim3((256*256*3+255)/256), dim3(256), 0, stream, W3, W3b, 256, 256);
  hipLaunchKernelGGL(pack_wp_kernel, dim3(32), dim3(256), 0, stream, Wp, Bwp);
  hipLaunchKernelGGL(f2bf_kernel, dim3((17039360+255)/256), dim3(256), 0, stream, Wfc1, Wfc1b, 17039360);

  for (int c = 0; c < NC; ++c){
    const float* xc = x + (size_t)c*Bc*16384;
    // zero guards: h0 buf (buf1 as [Bc][257][64]) and conv1out (buf2 as [Bc][257][128])
    hipLaunchKernelGGL(zero_guards_kernel, dim3((Bc*2*64/8+255)/256), dim3(256), 0, stream,
                       buf1, 257, 64, Bc);
    hipLaunchKernelGGL(zero_guards_kernel, dim3((Bc*2*128/8+255)/256), dim3(256), 0, stream,
                       buf2, 257, 128, Bc);
    hipLaunchKernelGGL(branch_kernel, dim3(Bc), dim3(256), 0, stream,
                       xc, Wb1, bb1, Wb2, bb2, Wb3, bb3, Hcat);
    hipLaunchKernelGGL(h0_gemm_kernel, dim3(Bc*255/128), dim3(256), 0, stream, xc, Bwp, bp, buf1);
    // conv1: 64->128, S=1, padded 257 -> padded 257x128 ; M = Bc*255
    hipLaunchKernelGGL((conv_gemm_kernel<64,128,1,257,255,false>), dim3(Bc*255/128, 1), dim3(256), 0, stream,
                       buf1, W1b, b1, buf2);
    // conv2out guards alias h0 data in buf1 -> zero them only after conv1 consumed buf1
    hipLaunchKernelGGL(zero_guards_kernel, dim3((Bc*2*256/8+255)/256), dim3(256), 0, stream,
                       buf1, 130, 256, Bc);
    // conv2: 128->256, S=2, padded 257 -> padded 130x256 ; M = Bc*128
    hipLaunchKernelGGL((conv_gemm_kernel<128,256,2,257,128,false>), dim3(Bc, 2), dim3(256), 0, stream,
                       buf2, W2b, b2, buf1);
    // conv3: 256->256, S=2, padded 130 -> Hcat channel-major ; M = Bc*64
    hipLaunchKernelGGL((conv_gemm_kernel<256,256,2,130,64,true>), dim3(Bc/2, 2), dim3(256), 0, stream,
                       buf1, W3b, b3, Hcat);
    hipLaunchKernelGGL(fc1_gemm_kernel, dim3(8*MT*KZ), dim3(256), 0, stream,
                       Hcat, Wfc1b, zp, zoffm, MT, KZ);
    hipLaunchKernelGGL(fc2_kernel, dim3(Bc), dim3(256), 0, stream,
                       zp, zoffm, KZ, bfc1, Wfc2, bfc2, out + (size_t)c*Bc*2);
  }
}